// Round 10
// baseline (212.790 us; speedup 1.0000x reference)
//
#include <hip/hip_runtime.h>
#include <hip/hip_bf16.h>
#include <math.h>

typedef __hip_bfloat16 bf16;
typedef __attribute__((ext_vector_type(8))) short s16x8;
typedef __attribute__((ext_vector_type(4))) float f32x4;

__device__ __forceinline__ float siluf(float x) { return x / (1.f + __expf(-x)); }
__device__ __forceinline__ float bits2f(unsigned short u) {
    union { float f; unsigned i; } v; v.i = ((unsigned)u) << 16; return v.f;
}
__device__ __forceinline__ unsigned short f2bits(float f) {
    return (unsigned short)__bfloat16_as_ushort(__float2bfloat16(f));
}

// ---------------- workspace offsets (float units) ----------------
#define KFL 1024
#define OFF_UB   (768*KFL)
#define OFF_DTV  (1280*KFL)
#define OFF_BMB  (1344*KFL)
#define OFF_CMB  (2368*KFL)
#define OFF_ZGB  (3392*KFL)
#define OFF_XB   (3904*KFL)
#define OFF_YGB  (7488*KFL)
#define OFF_Z2   (8000*KFL)
#define OFF_ZFB  (9024*KFL)
#define OFF_GG   OFF_BMB

// weight element offsets (bf16 elements, from ws base)
#define W_BCZX 0
#define W_OUT  393216
#define W_QKV  458752
#define W_AO   655360
#define W_GU   720896
#define W_D    1245184

// ======== combo1: weight prep (blocks 0..367) + LN1+dt (blocks 368..4463) ========
__global__ __launch_bounds__(256) void prep_ln1_kernel(
    const float* __restrict__ Wx, const float* __restrict__ Wb,
    const float* __restrict__ Wc, const float* __restrict__ Wz,
    const float* __restrict__ Wo, const float* __restrict__ Wqkv,
    const float* __restrict__ Wao, const float* __restrict__ Wg,
    const float* __restrict__ Wu, const float* __restrict__ Wd,
    const float* __restrict__ U, const float* __restrict__ V,
    unsigned short* __restrict__ wout,
    const float* __restrict__ z, const float* __restrict__ g1,
    const float* __restrict__ b1, const float* __restrict__ Wdt,
    const float* __restrict__ dt_bias,
    unsigned short* __restrict__ u, float4* __restrict__ dtv4)
{
    __shared__ __align__(16) float smem[64 * 65];
    int blk = blockIdx.x;
    int tid = threadIdx.x;
    if (blk < 368) {
        if (blk >= 304) {
            int off = blk - 304;
            const float* src; int dst, base;
            if (off < 48) { src = Wqkv; dst = W_QKV; base = off * 4096; }
            else          { src = Wao;  dst = W_AO;  base = (off - 48) * 4096; }
            #pragma unroll
            for (int i = 0; i < 16; i++) {
                int idx = base + tid + i * 256;
                wout[dst + idx] = f2bits(src[idx]);
            }
            return;
        }
        float* lds = smem;
        const float* src; int srcN, n0, sc0, k0, dstoff, dstK, mix = 0, t;
        if (blk < 32)       { t = blk;       src = Wb; srcN = 512;  dstoff = W_BCZX; dstK = 256;
                              n0 = (t >> 2) * 64;        sc0 = 0; k0 = (t & 3) * 64; mix = 1; }
        else if (blk < 64)  { t = blk - 32;  src = Wc; srcN = 512;  dstoff = W_BCZX; dstK = 256;
                              n0 = 512 + (t >> 2) * 64;  sc0 = (t >> 2) * 64; k0 = (t & 3) * 64; }
        else if (blk < 80)  { t = blk - 64;  src = Wz; srcN = 256;  dstoff = W_BCZX; dstK = 256;
                              n0 = 1024 + (t >> 2) * 64; sc0 = (t >> 2) * 64; k0 = (t & 3) * 64; }
        else if (blk < 96)  { t = blk - 80;  src = Wx; srcN = 256;  dstoff = W_BCZX; dstK = 256;
                              n0 = 1280 + (t >> 2) * 64; sc0 = (t >> 2) * 64; k0 = (t & 3) * 64; }
        else if (blk < 112) { t = blk - 96;  src = Wo; srcN = 256;  dstoff = W_OUT;  dstK = 256;
                              n0 = (t >> 2) * 64;        sc0 = n0; k0 = (t & 3) * 64; }
        else if (blk < 176) { t = blk - 112; src = Wg; srcN = 1024; dstoff = W_GU;   dstK = 256;
                              n0 = (t >> 2) * 64;        sc0 = n0; k0 = (t & 3) * 64; }
        else if (blk < 240) { t = blk - 176; src = Wu; srcN = 1024; dstoff = W_GU;   dstK = 256;
                              n0 = 1024 + (t >> 2) * 64; sc0 = (t >> 2) * 64; k0 = (t & 3) * 64; }
        else                { t = blk - 240; src = Wd; srcN = 256;  dstoff = W_D;    dstK = 1024;
                              n0 = (t >> 4) * 64;        sc0 = n0; k0 = (t & 15) * 64; }
        if (mix) {
            int h = n0 >> 7, scol = n0 & 127;
            float mm[4];
            #pragma unroll
            for (int g = 0; g < 4; g++) {
                float s = 0.f;
                #pragma unroll
                for (int j = 0; j < 4; j++) s += U[h * 4 + j] * V[g * 4 + j];
                mm[g] = s;
            }
            #pragma unroll
            for (int i = 0; i < 16; i++) {
                int idx = tid + i * 256;
                int kk = idx >> 6, nn = idx & 63;
                const float* row = src + (size_t)(k0 + kk) * 512 + scol + nn;
                lds[kk * 65 + nn] = mm[0] * row[0] + mm[1] * row[128]
                                  + mm[2] * row[256] + mm[3] * row[384];
            }
        } else {
            #pragma unroll
            for (int i = 0; i < 16; i++) {
                int idx = tid + i * 256;
                int kk = idx >> 6, nn = idx & 63;
                lds[kk * 65 + nn] = src[(size_t)(k0 + kk) * srcN + sc0 + nn];
            }
        }
        __syncthreads();
        #pragma unroll
        for (int i = 0; i < 16; i++) {
            int idx = tid + i * 256;
            int nn = idx >> 6, kk = idx & 63;
            wout[dstoff + (size_t)(n0 + nn) * dstK + k0 + kk] = f2bits(lds[kk * 65 + nn]);
        }
        return;
    }
    // ---- LN1 + dt path ----
    int r = blk - 368;
    float* lds = smem;          // 4 floats
    float* dts = smem + 4;      // 16 floats
    int t = r & 255, bk = r >> 8;
    int b_ = bk >> 3, k = bk & 7;
    int srcr = ((b_ * 256 + t) * 8 + k) * 256;
    int d = tid;
    float x = z[srcr + d];
    float v = x;
    #pragma unroll
    for (int off = 32; off; off >>= 1) v += __shfl_xor(v, off, 64);
    if ((d & 63) == 0) lds[d >> 6] = v;
    __syncthreads();
    float mean = (lds[0] + lds[1] + lds[2] + lds[3]) * (1.f / 256.f);
    __syncthreads();
    float c = x - mean;
    v = c * c;
    #pragma unroll
    for (int off = 32; off; off >>= 1) v += __shfl_xor(v, off, 64);
    if ((d & 63) == 0) lds[d >> 6] = v;
    __syncthreads();
    float var = (lds[0] + lds[1] + lds[2] + lds[3]) * (1.f / 256.f);
    float uval = c * rsqrtf(var + 1e-5f) * g1[d] + b1[d];
    u[r * 256 + d] = f2bits(uval);
    float4 wv = *(const float4*)(Wdt + d * 4);
    float q0 = uval * wv.x, q1 = uval * wv.y, q2 = uval * wv.z, q3 = uval * wv.w;
    #pragma unroll
    for (int off = 32; off; off >>= 1) {
        q0 += __shfl_xor(q0, off, 64);
        q1 += __shfl_xor(q1, off, 64);
        q2 += __shfl_xor(q2, off, 64);
        q3 += __shfl_xor(q3, off, 64);
    }
    if ((d & 63) == 0) {
        int w = d >> 6;
        dts[w * 4 + 0] = q0; dts[w * 4 + 1] = q1;
        dts[w * 4 + 2] = q2; dts[w * 4 + 3] = q3;
    }
    __syncthreads();
    if (d == 0) {
        float dv[4];
        #pragma unroll
        for (int h = 0; h < 4; h++) {
            float xx = dts[h] + dts[4 + h] + dts[8 + h] + dts[12 + h] + dt_bias[h];
            dv[h] = (xx > 20.f) ? xx : log1pf(__expf(xx));
        }
        dtv4[r] = make_float4(dv[0], dv[1], dv[2], dv[3]);
    }
}

// -------- mega GEMM BCZX: 64x128 tile, BK=64 pipelined, 768 blocks (3/CU) --------
__global__ __launch_bounds__(256) void gemm_bczx(
    const unsigned short* __restrict__ A, const unsigned short* __restrict__ Bt,
    unsigned short* __restrict__ bmb, unsigned short* __restrict__ cmb,
    unsigned short* __restrict__ zgb, unsigned short* __restrict__ xb)
{
    __shared__ __align__(16) unsigned short As[64 * 72];
    __shared__ __align__(16) unsigned short Bs[128 * 72];
    const int K = 256;
    int tid = threadIdx.x;
    int n0 = blockIdx.x * 128, m0 = blockIdx.y * 64;
    int w = tid >> 6, l = tid & 63;
    int mwave = (w >> 1) * 32, nwave = (w & 1) * 64;
    f32x4 acc[2][4] = {};
    int srow = tid >> 3, sc = (tid & 7) * 8;
    const unsigned short* Ap = A + (size_t)(m0 + srow) * K + sc;
    const unsigned short* Bp = Bt + (size_t)(n0 + srow) * K + sc;
    int lq = l & 15, lh = l >> 4;
    uint4 a0 = *(const uint4*)(Ap);
    uint4 a1 = *(const uint4*)(Ap + (size_t)32 * K);
    uint4 b0 = *(const uint4*)(Bp);
    uint4 b1 = *(const uint4*)(Bp + (size_t)32 * K);
    uint4 b2 = *(const uint4*)(Bp + (size_t)64 * K);
    uint4 b3 = *(const uint4*)(Bp + (size_t)96 * K);
    for (int k0 = 0; k0 < K; k0 += 64) {
        if (k0) __syncthreads();
        *(uint4*)&As[srow * 72 + sc] = a0;
        *(uint4*)&As[(srow + 32) * 72 + sc] = a1;
        *(uint4*)&Bs[srow * 72 + sc] = b0;
        *(uint4*)&Bs[(srow + 32) * 72 + sc] = b1;
        *(uint4*)&Bs[(srow + 64) * 72 + sc] = b2;
        *(uint4*)&Bs[(srow + 96) * 72 + sc] = b3;
        __syncthreads();
        if (k0 + 64 < K) {
            a0 = *(const uint4*)(Ap + k0 + 64);
            a1 = *(const uint4*)(Ap + (size_t)32 * K + k0 + 64);
            b0 = *(const uint4*)(Bp + k0 + 64);
            b1 = *(const uint4*)(Bp + (size_t)32 * K + k0 + 64);
            b2 = *(const uint4*)(Bp + (size_t)64 * K + k0 + 64);
            b3 = *(const uint4*)(Bp + (size_t)96 * K + k0 + 64);
        }
        #pragma unroll
        for (int kk = 0; kk < 2; kk++) {
            int kof = kk * 32 + lh * 8;
            s16x8 bfr[4];
            #pragma unroll
            for (int nf = 0; nf < 4; nf++)
                bfr[nf] = *(const s16x8*)&Bs[(nwave + nf * 16 + lq) * 72 + kof];
            #pragma unroll
            for (int mf = 0; mf < 2; mf++) {
                s16x8 af = *(const s16x8*)&As[(mwave + mf * 16 + lq) * 72 + kof];
                #pragma unroll
                for (int nf = 0; nf < 4; nf++)
                    acc[mf][nf] = __builtin_amdgcn_mfma_f32_16x16x32_bf16(af, bfr[nf], acc[mf][nf], 0, 0, 0);
            }
        }
    }
    #pragma unroll
    for (int mf = 0; mf < 2; mf++) {
        #pragma unroll
        for (int nf = 0; nf < 4; nf++) {
            int n = n0 + nwave + nf * 16 + lq;
            #pragma unroll
            for (int r = 0; r < 4; r++) {
                int m = m0 + mwave + mf * 16 + lh * 4 + r;
                float v = acc[mf][nf][r];
                if (n < 512)       bmb[(size_t)m * 512 + n] = f2bits(v);
                else if (n < 1024) cmb[(size_t)m * 512 + (n - 512)] = f2bits(v);
                else if (n < 1280) zgb[(size_t)m * 256 + (n - 1024)] = f2bits(siluf(v));
                else               xb[(size_t)m * 256 + (n - 1280)] = f2bits(v);
            }
        }
    }
}

// ======== score_kernel: fused gemm_s + conv + gemm_y, P and x2t live in LDS ========
// grid (4, 64): by strip of 64 t-rows, bh = band*4+head; 512 threads / 8 waves
__global__ __launch_bounds__(512) void score_kernel(
    const unsigned short* __restrict__ cmb, const unsigned short* __restrict__ bmb,
    const float4* __restrict__ dtv4, const float* __restrict__ A_log,
    const float* __restrict__ theta,
    const unsigned short* __restrict__ xb, const float* __restrict__ cw,
    const unsigned short* __restrict__ zgb, const float* __restrict__ Dsk,
    unsigned short* __restrict__ ygb)
{
    __shared__ __align__(16) char smem[62976];
    unsigned short* Pl  = (unsigned short*)smem;             // [64][264] = 33792 B
    unsigned short* As2 = (unsigned short*)(smem + 33792);   // [64][132] = 16896 B
    unsigned short* Bs  = (unsigned short*)(smem + 50688);   // [64][72]  = 9216 B
    unsigned short* Xc  = (unsigned short*)(smem + 33792);   // overlay As2 after P-phase
    float* mAs = (float*)(smem + 59904);                     // 256
    float* phs = mAs + 256;
    float* dss = phs + 256;

    int by = blockIdx.x;        // 0..3 -> t strip [by*64, by*64+64)
    int bh = blockIdx.y;        // 0..63
    int bk = bh >> 2, h = bh & 3;
    int tid = threadIdx.x;
    int w = tid >> 6, l = tid & 63;
    int lq = l & 15, lh = l >> 4;
    int srow2 = tid >> 3, sc2 = (tid & 7) * 8;

    // early loads (overlap the scan)
    uint4 ax0, ax1;
    {
        int uid0 = tid, uid1 = tid + 512;
        ax0 = *(const uint4*)(cmb + (size_t)(bk * 256 + by * 64 + (uid0 >> 4)) * 512 + h * 128 + (uid0 & 15) * 8);
        ax1 = *(const uint4*)(cmb + (size_t)(bk * 256 + by * 64 + (uid1 >> 4)) * 512 + h * 128 + (uid1 & 15) * 8);
    }
    uint4 bl = *(const uint4*)(bmb + (size_t)(bk * 256 + srow2) * 512 + h * 128 + sc2);
    float4 cwv = *(const float4*)(cw + (h * 64 + l) * 4);

    // ---- dt scan over t=0..255 (threads 0..255 meaningful) ----
    {
        float dth = 0.f;
        if (tid < 256) {
            float4 dv = dtv4[bk * 256 + tid];
            dth = (h == 0) ? dv.x : (h == 1) ? dv.y : (h == 2) ? dv.z : dv.w;
            dss[tid] = dth;
        }
        float Ah = -__expf(A_log[h]);
        float th = theta[h];
        float sa = dth * Ah, sp = dth * th;
        int lane = tid & 63, wv = tid >> 6;
        #pragma unroll
        for (int off = 1; off < 64; off <<= 1) {
            float ta = __shfl_up(sa, off, 64);
            float tp = __shfl_up(sp, off, 64);
            if (lane >= off) { sa += ta; sp += tp; }
        }
        if (tid < 256 && lane == 63) { mAs[wv] = sa; phs[wv] = sp; }
        __syncthreads();
        float offA = 0.f, offP = 0.f;
        #pragma unroll
        for (int j = 0; j < 3; j++)
            if (j < wv) { offA += mAs[j]; offP += phs[j]; }
        __syncthreads();
        if (tid < 256) { mAs[tid] = sa + offA; phs[tid] = sp + offP; }
    }
    // stage A (cmb strip, 64 x 128) into As2
    {
        int uid0 = tid, uid1 = tid + 512;
        *(uint4*)&As2[(uid0 >> 4) * 132 + (uid0 & 15) * 8] = ax0;
        *(uint4*)&As2[(uid1 >> 4) * 132 + (uid1 & 15) * 8] = ax1;
    }

    // ---- P strip: P[t_local][s] for s in [0, kmax), K=128 over h channels ----
    int mwP = (w & 3) * 16, nwP = (w >> 2) * 32;
    for (int nc = 0; nc <= by; nc++) {
        f32x4 pacc[2] = {};
        #pragma unroll
        for (int k0 = 0; k0 < 128; k0 += 64) {
            __syncthreads();
            *(uint4*)&Bs[srow2 * 72 + sc2] = bl;
            __syncthreads();
            {
                int nnc = nc, nk0 = k0 + 64;
                if (nk0 == 128) { nnc = nc + 1; nk0 = 0; }
                if (nnc <= by)
                    bl = *(const uint4*)(bmb + (size_t)(bk * 256 + nnc * 64 + srow2) * 512 + h * 128 + nk0 + sc2);
            }
            #pragma unroll
            for (int kk = 0; kk < 2; kk++) {
                int kof = kk * 32 + lh * 8;
                s16x8 af = *(const s16x8*)&As2[(mwP + lq) * 132 + k0 + kof];
                #pragma unroll
                for (int nf = 0; nf < 2; nf++) {
                    s16x8 bf = *(const s16x8*)&Bs[(nwP + nf * 16 + lq) * 72 + kof];
                    pacc[nf] = __builtin_amdgcn_mfma_f32_16x16x32_bf16(af, bf, pacc[nf], 0, 0, 0);
                }
            }
        }
        // decay-weight epilogue -> P LDS (bf16, identical rounding to old global path)
        float tmv[4], tpv[4]; int tg[4];
        #pragma unroll
        for (int r = 0; r < 4; r++) {
            tg[r] = by * 64 + mwP + lh * 4 + r;
            tmv[r] = mAs[tg[r]];
            tpv[r] = phs[tg[r]];
        }
        #pragma unroll
        for (int nf = 0; nf < 2; nf++) {
            int s = nc * 64 + nwP + nf * 16 + lq;
            float ms = mAs[s];
            float ps = phs[s];
            float ds = dss[s];
            #pragma unroll
            for (int r = 0; r < 4; r++) {
                float wgt = (s <= tg[r])
                    ? __expf(tmv[r] - ms) * __cosf(tpv[r] - ps) * ds : 0.f;
                Pl[(mwP + lh * 4 + r) * 264 + s] = f2bits(pacc[nf][r] * wgt);
            }
        }
    }

    // ---- Y = P @ X^T, X chunks computed in-block by conv ----
    int mwY = (w >> 2) * 32, nwY = (w & 3) * 16;
    f32x4 yacc[2] = {};
    float xvv[2][4];
    for (int sc = 0; sc <= by; sc++) {
        __syncthreads();   // As2/Bs reads & previous Xc reads done; P writes visible
        // conv chunk: x2t[p][t_abs] for t_abs in [sc*64, sc*64+64), p = lane
        #pragma unroll
        for (int i = 0; i < 8; i++) {
            int tl = w + i * 8;
            int t_abs = sc * 64 + tl;
            float a = 0.f;
            #pragma unroll
            for (int j = 0; j < 4; j++) {
                int tr = t_abs - 3 + j;
                float xj = (tr >= 0) ? bits2f(xb[(size_t)(bk * 256 + tr) * 256 + h * 64 + l]) : 0.f;
                float wj = (j == 0) ? cwv.x : (j == 1) ? cwv.y : (j == 2) ? cwv.z : cwv.w;
                a += xj * wj;
            }
            Xc[l * 72 + tl] = f2bits(siluf(a));
        }
        __syncthreads();
        if (sc == by) {
            #pragma unroll
            for (int mf = 0; mf < 2; mf++)
                #pragma unroll
                for (int r = 0; r < 4; r++)
                    xvv[mf][r] = bits2f(Xc[(nwY + lq) * 72 + mwY + mf * 16 + lh * 4 + r]);
        }
        #pragma unroll
        for (int ks = 0; ks < 2; ks++) {
            int kof = ks * 32 + lh * 8;
            s16x8 bf = *(const s16x8*)&Xc[(nwY + lq) * 72 + kof];
            #pragma unroll
            for (int mf = 0; mf < 2; mf++) {
                s16x8 af = *(const s16x8*)&Pl[(mwY + mf * 16 + lq) * 264 + sc * 64 + kof];
                yacc[mf] = __builtin_amdgcn_mfma_f32_16x16x32_bf16(af, bf, yacc[mf], 0, 0, 0);
            }
        }
    }
    // ---- skip + gate epilogue ----
    float dsk = Dsk[h];
    #pragma unroll
    for (int mf = 0; mf < 2; mf++) {
        #pragma unroll
        for (int r = 0; r < 4; r++) {
            int t_abs = by * 64 + mwY + mf * 16 + lh * 4 + r;
            int p = nwY + lq;
            size_t off = (size_t)(bk * 256 + t_abs) * 256 + h * 64 + p;
            float zg = bits2f(zgb[off]);
            ygb[off] = f2bits((yacc[mf][r] + dsk * xvv[mf][r]) * zg);
        }
    }
}

// ======== mid_kernel v4: 16 rows/block, 256 blocks, 512 thr / 8 waves ========
// continuous 2-deep register prefetch across all phases (issue-early/write-late)
__global__ __launch_bounds__(512) void mid_kernel(
    const unsigned short* __restrict__ ygb, const unsigned short* __restrict__ wts,
    const float* __restrict__ zin,
    const float* __restrict__ g2, const float* __restrict__ b2,
    const float* __restrict__ qbias, const float* __restrict__ obias,
    const float* __restrict__ g3, const float* __restrict__ b3,
    float* __restrict__ z2, unsigned short* __restrict__ zfb)
{
    __shared__ __align__(16) char smem[65024];
    unsigned short* Bs = (unsigned short*)smem;             // 256*72*2 = 36864
    unsigned short* As = (unsigned short*)(smem + 36864);   // 16*72*2  = 2304
    unsigned short* zn = (unsigned short*)(smem + 39168);   // 16*264*2 = 8448 (znb, later ob)
    float* z1s = (float*)(smem + 47616);                    // 16*256*4 = 16384
    float (*partS)[8] = (float(*)[8])(smem + 64000);        // 512
    float (*partQ)[8] = (float(*)[8])(smem + 64512);        // 512
    unsigned short* qk = (unsigned short*)smem;             // overlay Bs: 16*776*2 = 24832

    const int K = 256;
    int tid = threadIdx.x;
    int m0 = blockIdx.x * 16;
    int w = tid >> 6, l = tid & 63;
    int nw = w * 32;                 // 8 waves x 32 cols
    int lq = l & 15, lh = l >> 4;
    int srow = tid >> 3, sc = (tid & 7) * 8;   // srow 0..63

    const unsigned short* BpO  = wts + W_OUT + (size_t)srow * K + sc;
    const unsigned short* BpQ0 = wts + W_QKV + (size_t)srow * K + sc;
    const unsigned short* BpQ1 = BpQ0 + (size_t)256 * K;
    const unsigned short* BpQ2 = BpQ0 + (size_t)512 * K;
    const unsigned short* BpA  = wts + W_AO + (size_t)srow * K + sc;

    uint4 wA0, wA1, wA2, wA3, wB0, wB1, wB2, wB3;

#define LOADW(P, BASE, KO) do { \
    P##0 = *(const uint4*)((BASE) + (KO)); \
    P##1 = *(const uint4*)((BASE) + (size_t)64 * K + (KO)); \
    P##2 = *(const uint4*)((BASE) + (size_t)128 * K + (KO)); \
    P##3 = *(const uint4*)((BASE) + (size_t)192 * K + (KO)); \
} while (0)
#define STORE_BS(P) do { \
    *(uint4*)&Bs[srow * 72 + sc] = P##0; \
    *(uint4*)&Bs[(srow + 64) * 72 + sc] = P##1; \
    *(uint4*)&Bs[(srow + 128) * 72 + sc] = P##2; \
    *(uint4*)&Bs[(srow + 192) * 72 + sc] = P##3; \
} while (0)
#define MM_ZN(AQ, KO) do { \
    _Pragma("unroll") \
    for (int kk = 0; kk < 2; kk++) { \
        int kof = kk * 32 + lh * 8; \
        s16x8 af = *(const s16x8*)&zn[lq * 264 + (KO) + kof]; \
        _Pragma("unroll") \
        for (int nf = 0; nf < 2; nf++) { \
            s16x8 bf = *(const s16x8*)&Bs[(nw + nf * 16 + lq) * 72 + kof]; \
            AQ[nf] = __builtin_amdgcn_mfma_f32_16x16x32_bf16(af, bf, AQ[nf], 0, 0, 0); \
        } \
    } \
} while (0)
#define MM_AS(AQ) do { \
    _Pragma("unroll") \
    for (int kk = 0; kk < 2; kk++) { \
        int kof = kk * 32 + lh * 8; \
        s16x8 af = *(const s16x8*)&As[lq * 72 + kof]; \
        _Pragma("unroll") \
        for (int nf = 0; nf < 2; nf++) { \
            s16x8 bf = *(const s16x8*)&Bs[(nw + nf * 16 + lq) * 72 + kof]; \
            AQ[nf] = __builtin_amdgcn_mfma_f32_16x16x32_bf16(af, bf, AQ[nf], 0, 0, 0); \
        } \
    } \
} while (0)

    // ------------- phase 1: z1 = ygb(gathered) @ Wout + z ; zn = LN2(z1) -------------
    f32x4 acc1[2] = {};
    {
        int rb = m0 + (srow & 15);
        int irow = ((rb >> 11) * 8 + (rb & 7)) * 256 + ((rb >> 3) & 255);
        const unsigned short* Ap = ygb + (size_t)irow * K + sc;
        LOADW(wA, BpO, 0);
        LOADW(wB, BpO, 64);
        uint4 aP = *(const uint4*)(Ap);
        uint4 aQ;
        // r0 (k0=0)
        __syncthreads();
        if (tid < 128) *(uint4*)&As[srow * 72 + sc] = aP;
        STORE_BS(wA);
        __syncthreads();
        aQ = *(const uint4*)(Ap + 64);
        LOADW(wA, BpO, 128);
        MM_AS(acc1);
        // r1 (k0=64)
        __syncthreads();
        if (tid < 128) *(uint4*)&As[srow * 72 + sc] = aQ;
        STORE_BS(wB);
        __syncthreads();
        aP = *(const uint4*)(Ap + 128);
        LOADW(wB, BpO, 192);
        MM_AS(acc1);
        // r2 (k0=128) — prefetch QKV pass0 k0=0
        __syncthreads();
        if (tid < 128) *(uint4*)&As[srow * 72 + sc] = aP;
        STORE_BS(wA);
        __syncthreads();
        aQ = *(const uint4*)(Ap + 192);
        LOADW(wA, BpQ0, 0);
        MM_AS(acc1);
        // r3 (k0=192) — prefetch QKV pass0 k0=64
        __syncthreads();
        if (tid < 128) *(uint4*)&As[srow * 72 + sc] = aQ;
        STORE_BS(wB);
        __syncthreads();
        LOADW(wB, BpQ0, 64);
        MM_AS(acc1);
        // epilogue: residual + LN2 (QKV pass0 loads in flight)
        #pragma unroll
        for (int r = 0; r < 4; r++) {
            int row = lh * 4 + r;
            float s = 0.f, q = 0.f;
            #pragma unroll
            for (int nf = 0; nf < 2; nf++) {
                float v = acc1[nf][r] + zin[(size_t)(m0 + row) * 256 + nw + nf * 16 + lq];
                acc1[nf][r] = v;
                s += v; q += v * v;
            }
            #pragma unroll
            for (int off = 1; off < 16; off <<= 1) {
                s += __shfl_xor(s, off, 64);
                q += __shfl_xor(q, off, 64);
            }
            if (lq == 0) { partS[row][w] = s; partQ[row][w] = q; }
        }
        __syncthreads();
        float gv[2], bbv[2];
        #pragma unroll
        for (int nf = 0; nf < 2; nf++) {
            gv[nf] = g2[nw + nf * 16 + lq];
            bbv[nf] = b2[nw + nf * 16 + lq];
        }
        #pragma unroll
        for (int r = 0; r < 4; r++) {
            int row = lh * 4 + r;
            float sum = 0.f, sq = 0.f;
            #pragma unroll
            for (int j = 0; j < 8; j++) { sum += partS[row][j]; sq += partQ[row][j]; }
            float mean = sum * (1.f / 256.f);
            float var = sq * (1.f / 256.f) - mean * mean;
            float rstd = rsqrtf(var + 1e-5f);
            #pragma unroll
            for (int nf = 0; nf < 2; nf++) {
                int n = nw + nf * 16 + lq;
                float v = acc1[nf][r];
                z1s[row * 256 + n] = v;
                zn[row * 264 + n] = f2bits((v - mean) * rstd * gv[nf] + bbv[nf]);
            }
        }
    }

    // ------------- phase 2: qkv = zn @ Wqkv, 12 rounds, continuous 2-deep -------------
    f32x4 aq0[2] = {}, aq1[2] = {}, aq2[2] = {};
#define RND(P, AQ, KO, NBASE, NKO) do { \
    __syncthreads(); \
    STORE_BS(P); \
    __syncthreads(); \
    LOADW(P, NBASE, NKO); \
    MM_ZN(AQ, KO); \
} while (0)
#define RND_NL(P, AQ, KO) do { \
    __syncthreads(); \
    STORE_BS(P); \
    __syncthreads(); \
    MM_ZN(AQ, KO); \
} while (0)
    RND(wA, aq0, 0,   BpQ0, 128);
    RND(wB, aq0, 64,  BpQ0, 192);
    RND(wA, aq0, 128, BpQ1, 0);
    RND(wB, aq0, 192, BpQ1, 64);
    RND(wA, aq1, 0,   BpQ1, 128);
    RND(wB, aq1, 64,  BpQ1, 192);
    RND(wA, aq1, 128, BpQ2, 0);
    RND(wB, aq1, 192, BpQ2, 64);
    RND(wA, aq2, 0,   BpQ2, 128);
    RND(wB, aq2, 64,  BpQ2, 192);
    RND(wA, aq2, 128, BpA, 0);      // prefetch Wao k0=0 — flies through attention
    RND(wB, aq2, 192, BpA, 64);     // prefetch Wao k0=64

    // ------------- phase 3: qkv -> LDS (+bias), then attention -------------
    __syncthreads();   // all Bs reads done; safe to overwrite as qk
#define QKV_STORE(PIDX, AQ) do { \
    _Pragma("unroll") \
    for (int nf = 0; nf < 2; nf++) { \
        int n = (PIDX) * 256 + nw + nf * 16 + lq; \
        float bb = qbias[n]; \
        _Pragma("unroll") \
        for (int r = 0; r < 4; r++) \
            qk[(lh * 4 + r) * 776 + n] = f2bits(AQ[nf][r] + bb); \
    } \
} while (0)
    QKV_STORE(0, aq0);
    QKV_STORE(1, aq1);
    QKV_STORE(2, aq2);
#undef QKV_STORE
    __syncthreads();
    {
        int hh = w & 3;          // head
        int half = w >> 2;       // which pair of window-groups
        int d = l;
        #pragma unroll
        for (int wi = 0; wi < 2; wi++) {
            int w4 = half * 2 + wi;
            int r0 = w4 * 4;
            float qv[4], kv[4], vv[4];
            #pragma unroll
            for (int j = 0; j < 4; j++) {
                qv[j] = bits2f(qk[(r0 + j) * 776 + hh * 64 + d]);
                kv[j] = bits2f(qk[(r0 + j) * 776 + 256 + hh * 64 + d]);
                vv[j] = bits2f(qk[(r0 + j) * 776 + 512 + hh * 64 + d]);
            }
            float sc_[4][4];
            #pragma unroll
            for (int qi = 0; qi < 4; qi++)
                #pragma unroll
                for (int ki = 0; ki < 4; ki++) {
                    float v = qv[qi] * kv[ki];
                    #pragma unroll
                    for (int off = 32; off; off >>= 1) v += __shfl_xor(v, off, 64);
                    sc_[qi][ki] = v * 0.125f;
                }
            #pragma unroll
            for (int qi = 0; qi < 4; qi++) {
                float mx = fmaxf(fmaxf(sc_[qi][0], sc_[qi][1]), fmaxf(sc_[qi][2], sc_[qi][3]));
                float e0 = __expf(sc_[qi][0] - mx), e1 = __expf(sc_[qi][1] - mx);
                float e2 = __expf(sc_[qi][2] - mx), e3 = __expf(sc_[qi][3] - mx);
                float inv = 1.f / (e0 + e1 + e2 + e3);
                float ov = (e0 * vv[0] + e1 * vv[1] + e2 * vv[2] + e3 * vv[3]) * inv;
                zn[(r0 + qi) * 264 + hh * 64 + d] = f2bits(ov);   // ob overlays zn
            }
        }
    }

    // ------------- phase 4: z2 = ob @ Wao + obias + z1 ; zfb = LN3(z2) -------------
    {
        f32x4 ac4[2] = {};
        RND(wA, ac4, 0,  BpA, 128);
        RND(wB, ac4, 64, BpA, 192);
        RND_NL(wA, ac4, 128);
        RND_NL(wB, ac4, 192);
        float bv[2], gv[2], bbv[2];
        #pragma unroll
        for (int nf = 0; nf < 2; nf++) {
            int n = nw + nf * 16 + lq;
            bv[nf] = obias[n];
            gv[nf] = g3[n];
            bbv[nf] = b3[n];
        }
        #pragma unroll
        for (int r = 0; r < 4; r++) {
            int row = lh * 4 + r;
            float s = 0.f, q = 0.f;
            #pragma unroll
            for (int nf = 0; nf < 2; nf++) {
                float v = ac4[nf][r] + bv[nf] + z1s[row * 256 + nw + nf * 16 + lq];
                ac4[nf][r] = v;
                s += v; q += v * v;
            }
            #pragma unroll
            for (int off = 1; off < 16; off <<= 1) {
                s += __shfl_xor(s, off, 64);
                q += __shfl_xor(q, off, 64);
            }
            if (lq == 0) { partS[row][w] = s; partQ[row][w] = q; }
        }
        __syncthreads();
        #pragma unroll
        for (int r = 0; r < 4; r++) {
            int row = lh * 4 + r;
            float sum = 0.f, sq = 0.f;
            #pragma unroll
            for (int j = 0; j < 8; j++) { sum += partS[row][j]; sq += partQ[row][j]; }
            float mean = sum * (1.f / 256.f);
            float var = sq * (1.f / 256.f) - mean * mean;
            float rstd = rsqrtf(var + 1e-5f);
            size_t ro = (size_t)(m0 + row) * 256;
            #pragma unroll
            for (int nf = 0; nf < 2; nf++) {
                int n = nw + nf * 16 + lq;
                float v = ac4[nf][r];
                z2[ro + n] = v;
                zfb[ro + n] = f2bits((v - mean) * rstd * gv[nf] + bbv[nf]);
            }
        }
    }
#undef RND
#undef RND_NL
#undef LOADW
#undef STORE_BS
#undef MM_ZN
#undef MM_AS
}

// ---- gemm_gu2: 64x64 tile, dual-accumulator G/U, 1024 blocks (4/CU) ----
__global__ __launch_bounds__(256) void gemm_gu2(
    const unsigned short* __restrict__ A, const unsigned short* __restrict__ Wgu,
    unsigned short* __restrict__ gg)
{
    const int K = 256;
    __shared__ __align__(16) unsigned short As[64 * 72];
    __shared__ __align__(16) unsigned short Bgs[64 * 72];
    __shared__ __align__(16) unsigned short Bus[64 * 72];
    int tid = threadIdx.x;
    int n0 = blockIdx.x * 64, m0 = blockIdx.y * 64;
    int w = tid >> 6, l = tid & 63;
    int mwave = (w >> 1) * 32, nwave = (w & 1) * 32;
    int lq = l & 15, lh = l >> 4;
    f32x4 ag[2][2] = {}, au[2][2] = {};
    int srow = tid >> 3, sc = (tid & 7) * 8;
    const unsigned short* Ap = A + (size_t)(m0 + srow) * K + sc;
    const unsigned short* Bgp = Wgu + (size_t)(n0 + srow) * K + sc;
    const unsigned short* Bup = Wgu + (size_t)(1024 + n0 + srow) * K + sc;
    uint4 a0 = *(const uint4*)(Ap);
    uint4 a1 = *(const uint4*)(Ap + (size_t)32 * K);
    uint4 bg0 = *(const uint4*)(Bgp);
    uint4 bg1 = *(const uint4*)(Bgp + (size_t)32 * K);
    uint4 bu0 = *(const uint4*)(Bup);
    uint4 bu1 = *(const uint4*)(Bup + (size_t)32 * K);
    for (int k0 = 0; k0 < K; k0 += 64) {
        if (k0) __syncthreads();
        *(uint4*)&As[srow * 72 + sc] = a0;
        *(uint4*)&As[(srow + 32) * 72 + sc] = a1;
        *(uint4*)&Bgs[srow * 72 + sc] = bg0;
        *(uint4*)&Bgs[(srow + 32) * 72 + sc] = bg1;
        *(uint4*)&Bus[srow * 72 + sc] = bu0;
        *(uint4*)&Bus[(srow + 32) * 72 + sc] = bu1;
        __syncthreads();
        if (k0 + 64 < K) {
            a0 = *(const uint4*)(Ap + k0 + 64);
            a1 = *(const uint4*)(Ap + (size_t)32 * K + k0 + 64);
            bg0 = *(const uint4*)(Bgp + k0 + 64);
            bg1 = *(const uint4*)(Bgp + (size_t)32 * K + k0 + 64);
            bu0 = *(const uint4*)(Bup + k0 + 64);
            bu1 = *(const uint4*)(Bup + (size_t)32 * K + k0 + 64);
        }
        #pragma unroll
        for (int kk = 0; kk < 2; kk++) {
            int kof = kk * 32 + lh * 8;
            s16x8 bgr[2], bur[2];
            #pragma unroll
            for (int nf = 0; nf < 2; nf++) {
                bgr[nf] = *(const s16x8*)&Bgs[(nwave + nf * 16 + lq) * 72 + kof];
                bur[nf] = *(const s16x8*)&Bus[(nwave + nf * 16 + lq) * 72 + kof];
            }
            #pragma unroll
            for (int mf = 0; mf < 2; mf++) {
                s16x8 af = *(const s16x8*)&As[(mwave + mf * 16 + lq) * 72 + kof];
                #pragma unroll
                for (int nf = 0; nf < 2; nf++) {
                    ag[mf][nf] = __builtin_amdgcn_mfma_f32_16x16x32_bf16(af, bgr[nf], ag[mf][nf], 0, 0, 0);
                    au[mf][nf] = __builtin_amdgcn_mfma_f32_16x16x32_bf16(af, bur[nf], au[mf][nf], 0, 0, 0);
                }
            }
        }
    }
    #pragma unroll
    for (int mf = 0; mf < 2; mf++) {
        #pragma unroll
        for (int nf = 0; nf < 2; nf++) {
            int n = n0 + nwave + nf * 16 + lq;
            #pragma unroll
            for (int r = 0; r < 4; r++) {
                int m = m0 + mwave + mf * 16 + lh * 4 + r;
                gg[(size_t)m * 1024 + n] = f2bits(siluf(ag[mf][nf][r]) * au[mf][nf][r]);
            }
        }
    }
}

// ------- gemm_d2 (64x32 tile, BK=64, 2-deep register prefetch): out = gg @ Wd^T + resid -------
__global__ __launch_bounds__(256) void gemm_d2(
    const unsigned short* __restrict__ gg, const unsigned short* __restrict__ Bt,
    const float* __restrict__ resid, float* __restrict__ out)
{
    __shared__ __align__(16) unsigned short As[64 * 72];
    __shared__ __align__(16) unsigned short Bs[32 * 72];
    const int K = 1024, N = 256;
    int tid = threadIdx.x;
    int n0 = blockIdx.x * 32, m0 = blockIdx.y * 64;
    int w = tid >> 6, l = tid & 63;
    int mw = (w >> 1) * 32, nw = (w & 1) * 16;
    f32x4 acc[2] = {};
    int srow = tid >> 3, sc = (tid & 7) * 8;
    const unsigned short* Ap = gg + (size_t)(m0 + srow) * K + sc;
    const unsigned short* Bp = Bt + (size_t)(n0 + (srow & 31)) * K + sc;
    int lq = l & 15, lh = l >> 4;
    uint4 xA0 = *(const uint4*)(Ap);
    uint4 xA1 = *(const uint4*)(Ap + (size_t)32 * K);
    uint4 yA  = *(const uint4*)(Bp);
    uint4 xB0 = *(const uint4*)(Ap + 64);
    uint4 xB1 = *(const uint4*)(Ap + (size_t)32 * K + 64);
    uint4 yB  = *(const uint4*)(Bp + 64);
    for (int k0 = 0; k0 < K; k0 += 128) {
        __syncthreads();
        *(uint4*)&As[srow * 72 + sc] = xA0;
        *(uint4*)&As[(srow + 32) * 72 + sc] = xA1;
        *(uint4*)&Bs[(srow & 31) * 72 + sc] = yA;
        __syncthreads();
        if (k0 + 128 < K) {
            xA0 = *(const uint4*)(Ap + k0 + 128);
            xA1 = *(const uint4*)(Ap + (size_t)32 * K + k0 + 128);
            yA  = *(const uint4*)(Bp + k0 + 128);
        }
        #pragma unroll
        for (int kk = 0; kk < 2; kk++) {
            int kof = kk * 32 + lh * 8;
            s16x8 bf = *(const s16x8*)&Bs[(nw + lq) * 72 + kof];
            #pragma unroll
            for (int mf = 0; mf < 2; mf++) {
                s16x8 af = *(const s16x8*)&As[(mw + mf * 16 + lq) * 72 + kof];
                acc[mf] = __builtin_amdgcn_mfma_f32_16x16x32_bf16(af, bf, acc[mf], 0, 0, 0);
            }
        }
        __syncthreads();
        *(uint4*)&As[srow * 72 + sc] = xB0;
        *(uint4*)&As[(srow + 32) * 72 + sc] = xB1;
        *(uint4*)&Bs[(srow & 31) * 72 + sc] = yB;
        __syncthreads();
        if (k0 + 192 < K) {
            xB0 = *(const uint4*)(Ap + k0 + 192);
            xB1 = *(const uint4*)(Ap + (size_t)32 * K + k0 + 192);
            yB  = *(const uint4*)(Bp + k0 + 192);
        }
        #pragma unroll
        for (int kk = 0; kk < 2; kk++) {
            int kof = kk * 32 + lh * 8;
            s16x8 bf = *(const s16x8*)&Bs[(nw + lq) * 72 + kof];
            #pragma unroll
            for (int mf = 0; mf < 2; mf++) {
                s16x8 af = *(const s16x8*)&As[(mw + mf * 16 + lq) * 72 + kof];
                acc[mf] = __builtin_amdgcn_mfma_f32_16x16x32_bf16(af, bf, acc[mf], 0, 0, 0);
            }
        }
    }
    int n = n0 + nw + lq;
    #pragma unroll
    for (int mf = 0; mf < 2; mf++) {
        #pragma unroll
        for (int r = 0; r < 4; r++) {
            int m = m0 + mw + mf * 16 + lh * 4 + r;
            out[(size_t)m * N + n] = acc[mf][r] + resid[(size_t)m * N + n];
        }
    }
}

extern "C" void kernel_launch(void* const* d_in, const int* in_sizes, int n_in,
                              void* d_out, int out_size, void* d_ws, size_t ws_size,
                              hipStream_t stream)
{
    const float* z         = (const float*)d_in[0];
    const float* ln1_g     = (const float*)d_in[1];
    const float* ln1_b     = (const float*)d_in[2];
    const float* Wx        = (const float*)d_in[3];
    const float* conv_w    = (const float*)d_in[4];
    const float* Wz        = (const float*)d_in[5];
    const float* Wb        = (const float*)d_in[6];
    const float* Wc        = (const float*)d_in[7];
    const float* Wdt       = (const float*)d_in[8];
    const float* dt_bias   = (const float*)d_in[9];
    const float* A_log     = (const float*)d_in[10];
    const float* theta     = (const float*)d_in[11];
    const float* D_skip    = (const float*)d_in[12];
    const float* mimo_U    = (const float*)d_in[13];
    const float* mimo_V    = (const float*)d_in[14];
    const float* Wout      = (const float*)d_in[15];
    const float* ln2_g     = (const float*)d_in[16];
    const float* ln2_b     = (const float*)d_in[17];
    const float* attn_in_w = (const float*)d_in[18];
    const float* attn_in_b = (const float*)d_in[19];
    const float* attn_out_w= (const float*)d_in[20];
    const float* attn_out_b= (const float*)d_in[21];
    const float* ln3_g     = (const float*)d_in[22];
    const float* ln3_b     = (const float*)d_in[23];
    const float* Wg        = (const float*)d_in[24];
    const float* Wu        = (const float*)d_in[25];
    const float* Wd        = (const float*)d_in[26];

    float* W = (float*)d_ws;
    unsigned short* wts = (unsigned short*)W;
    unsigned short* ub  = (unsigned short*)(W + OFF_UB);
    float4* dtv4        = (float4*)(W + OFF_DTV);
    unsigned short* bmb = (unsigned short*)(W + OFF_BMB);
    unsigned short* cmb = (unsigned short*)(W + OFF_CMB);
    unsigned short* zgb = (unsigned short*)(W + OFF_ZGB);
    unsigned short* xb  = (unsigned short*)(W + OFF_XB);
    unsigned short* ygb = (unsigned short*)(W + OFF_YGB);
    float* z2           = W + OFF_Z2;
    unsigned short* zfb = (unsigned short*)(W + OFF_ZFB);
    unsigned short* gg  = (unsigned short*)(W + OFF_GG);

    prep_ln1_kernel<<<4464, 256, 0, stream>>>(
        Wx, Wb, Wc, Wz, Wout, attn_in_w, attn_out_w, Wg, Wu, Wd, mimo_U, mimo_V,
        wts, z, ln1_g, ln1_b, Wdt, dt_bias, ub, dtv4);
    gemm_bczx<<<dim3(12, 64), 256, 0, stream>>>(ub, wts + W_BCZX, bmb, cmb, zgb, xb);
    score_kernel<<<dim3(4, 64), 512, 0, stream>>>(cmb, bmb, dtv4, A_log, theta,
                                                  xb, conv_w, zgb, D_skip, ygb);
    mid_kernel<<<256, 512, 0, stream>>>(ygb, wts, z, ln2_g, ln2_b,
                                        attn_in_b, attn_out_b, ln3_g, ln3_b,
                                        z2, zfb);
    gemm_gu2<<<dim3(16, 64), 256, 0, stream>>>(zfb, wts + W_GU, gg);
    gemm_d2<<<dim3(8, 64), 256, 0, stream>>>(gg, wts + W_D, z2, (float*)d_out);
}

// Round 11
// 189.721 us; speedup vs baseline: 1.1216x; 1.1216x over previous
//
#include <hip/hip_runtime.h>
#include <hip/hip_bf16.h>
#include <math.h>

typedef __hip_bfloat16 bf16;
typedef __attribute__((ext_vector_type(8))) short s16x8;
typedef __attribute__((ext_vector_type(4))) float f32x4;

__device__ __forceinline__ float siluf(float x) { return x / (1.f + __expf(-x)); }
__device__ __forceinline__ float bits2f(unsigned short u) {
    union { float f; unsigned i; } v; v.i = ((unsigned)u) << 16; return v.f;
}
__device__ __forceinline__ unsigned short f2bits(float f) {
    return (unsigned short)__bfloat16_as_ushort(__float2bfloat16(f));
}

// ---------------- workspace offsets (float units) ----------------
#define KFL 1024
#define OFF_UB   (768*KFL)
#define OFF_DTV  (1280*KFL)
#define OFF_BMB  (1344*KFL)
#define OFF_CMB  (2368*KFL)
#define OFF_ZGB  (3392*KFL)
#define OFF_XB   (3904*KFL)
#define OFF_X2T  (4928*KFL)
#define OFF_P    (5440*KFL)
#define OFF_YGB  (7488*KFL)
#define OFF_Z2   (8000*KFL)
#define OFF_ZFB  (9024*KFL)
#define OFF_GG   OFF_BMB

// weight element offsets (bf16 elements, from ws base)
#define W_BCZX 0
#define W_OUT  393216
#define W_QKV  458752
#define W_AO   655360
#define W_GU   720896
#define W_D    1245184

// ======== combo1: weight prep (blocks 0..367) + LN1+dt (blocks 368..4463) ========
__global__ __launch_bounds__(256) void prep_ln1_kernel(
    const float* __restrict__ Wx, const float* __restrict__ Wb,
    const float* __restrict__ Wc, const float* __restrict__ Wz,
    const float* __restrict__ Wo, const float* __restrict__ Wqkv,
    const float* __restrict__ Wao, const float* __restrict__ Wg,
    const float* __restrict__ Wu, const float* __restrict__ Wd,
    const float* __restrict__ U, const float* __restrict__ V,
    unsigned short* __restrict__ wout,
    const float* __restrict__ z, const float* __restrict__ g1,
    const float* __restrict__ b1, const float* __restrict__ Wdt,
    const float* __restrict__ dt_bias,
    unsigned short* __restrict__ u, float4* __restrict__ dtv4)
{
    __shared__ __align__(16) float smem[64 * 65];
    int blk = blockIdx.x;
    int tid = threadIdx.x;
    if (blk < 368) {
        if (blk >= 304) {
            int off = blk - 304;
            const float* src; int dst, base;
            if (off < 48) { src = Wqkv; dst = W_QKV; base = off * 4096; }
            else          { src = Wao;  dst = W_AO;  base = (off - 48) * 4096; }
            #pragma unroll
            for (int i = 0; i < 16; i++) {
                int idx = base + tid + i * 256;
                wout[dst + idx] = f2bits(src[idx]);
            }
            return;
        }
        float* lds = smem;
        const float* src; int srcN, n0, sc0, k0, dstoff, dstK, mix = 0, t;
        if (blk < 32)       { t = blk;       src = Wb; srcN = 512;  dstoff = W_BCZX; dstK = 256;
                              n0 = (t >> 2) * 64;        sc0 = 0; k0 = (t & 3) * 64; mix = 1; }
        else if (blk < 64)  { t = blk - 32;  src = Wc; srcN = 512;  dstoff = W_BCZX; dstK = 256;
                              n0 = 512 + (t >> 2) * 64;  sc0 = (t >> 2) * 64; k0 = (t & 3) * 64; }
        else if (blk < 80)  { t = blk - 64;  src = Wz; srcN = 256;  dstoff = W_BCZX; dstK = 256;
                              n0 = 1024 + (t >> 2) * 64; sc0 = (t >> 2) * 64; k0 = (t & 3) * 64; }
        else if (blk < 96)  { t = blk - 80;  src = Wx; srcN = 256;  dstoff = W_BCZX; dstK = 256;
                              n0 = 1280 + (t >> 2) * 64; sc0 = (t >> 2) * 64; k0 = (t & 3) * 64; }
        else if (blk < 112) { t = blk - 96;  src = Wo; srcN = 256;  dstoff = W_OUT;  dstK = 256;
                              n0 = (t >> 2) * 64;        sc0 = n0; k0 = (t & 3) * 64; }
        else if (blk < 176) { t = blk - 112; src = Wg; srcN = 1024; dstoff = W_GU;   dstK = 256;
                              n0 = (t >> 2) * 64;        sc0 = n0; k0 = (t & 3) * 64; }
        else if (blk < 240) { t = blk - 176; src = Wu; srcN = 1024; dstoff = W_GU;   dstK = 256;
                              n0 = 1024 + (t >> 2) * 64; sc0 = (t >> 2) * 64; k0 = (t & 3) * 64; }
        else                { t = blk - 240; src = Wd; srcN = 256;  dstoff = W_D;    dstK = 1024;
                              n0 = (t >> 4) * 64;        sc0 = n0; k0 = (t & 15) * 64; }
        if (mix) {
            int h = n0 >> 7, scol = n0 & 127;
            float mm[4];
            #pragma unroll
            for (int g = 0; g < 4; g++) {
                float s = 0.f;
                #pragma unroll
                for (int j = 0; j < 4; j++) s += U[h * 4 + j] * V[g * 4 + j];
                mm[g] = s;
            }
            #pragma unroll
            for (int i = 0; i < 16; i++) {
                int idx = tid + i * 256;
                int kk = idx >> 6, nn = idx & 63;
                const float* row = src + (size_t)(k0 + kk) * 512 + scol + nn;
                lds[kk * 65 + nn] = mm[0] * row[0] + mm[1] * row[128]
                                  + mm[2] * row[256] + mm[3] * row[384];
            }
        } else {
            #pragma unroll
            for (int i = 0; i < 16; i++) {
                int idx = tid + i * 256;
                int kk = idx >> 6, nn = idx & 63;
                lds[kk * 65 + nn] = src[(size_t)(k0 + kk) * srcN + sc0 + nn];
            }
        }
        __syncthreads();
        #pragma unroll
        for (int i = 0; i < 16; i++) {
            int idx = tid + i * 256;
            int nn = idx >> 6, kk = idx & 63;
            wout[dstoff + (size_t)(n0 + nn) * dstK + k0 + kk] = f2bits(lds[kk * 65 + nn]);
        }
        return;
    }
    // ---- LN1 + dt path ----
    int r = blk - 368;
    float* lds = smem;          // 4 floats
    float* dts = smem + 4;      // 16 floats
    int t = r & 255, bk = r >> 8;
    int b_ = bk >> 3, k = bk & 7;
    int srcr = ((b_ * 256 + t) * 8 + k) * 256;
    int d = tid;
    float x = z[srcr + d];
    float v = x;
    #pragma unroll
    for (int off = 32; off; off >>= 1) v += __shfl_xor(v, off, 64);
    if ((d & 63) == 0) lds[d >> 6] = v;
    __syncthreads();
    float mean = (lds[0] + lds[1] + lds[2] + lds[3]) * (1.f / 256.f);
    __syncthreads();
    float c = x - mean;
    v = c * c;
    #pragma unroll
    for (int off = 32; off; off >>= 1) v += __shfl_xor(v, off, 64);
    if ((d & 63) == 0) lds[d >> 6] = v;
    __syncthreads();
    float var = (lds[0] + lds[1] + lds[2] + lds[3]) * (1.f / 256.f);
    float uval = c * rsqrtf(var + 1e-5f) * g1[d] + b1[d];
    u[r * 256 + d] = f2bits(uval);
    float4 wv = *(const float4*)(Wdt + d * 4);
    float q0 = uval * wv.x, q1 = uval * wv.y, q2 = uval * wv.z, q3 = uval * wv.w;
    #pragma unroll
    for (int off = 32; off; off >>= 1) {
        q0 += __shfl_xor(q0, off, 64);
        q1 += __shfl_xor(q1, off, 64);
        q2 += __shfl_xor(q2, off, 64);
        q3 += __shfl_xor(q3, off, 64);
    }
    if ((d & 63) == 0) {
        int w = d >> 6;
        dts[w * 4 + 0] = q0; dts[w * 4 + 1] = q1;
        dts[w * 4 + 2] = q2; dts[w * 4 + 3] = q3;
    }
    __syncthreads();
    if (d == 0) {
        float dv[4];
        #pragma unroll
        for (int h = 0; h < 4; h++) {
            float xx = dts[h] + dts[4 + h] + dts[8 + h] + dts[12 + h] + dt_bias[h];
            dv[h] = (xx > 20.f) ? xx : log1pf(__expf(xx));
        }
        dtv4[r] = make_float4(dv[0], dv[1], dv[2], dv[3]);
    }
}

// -------- mega GEMM BCZX: 64x128 tile, BK=64 pipelined, 768 blocks (3/CU) --------
__global__ __launch_bounds__(256) void gemm_bczx(
    const unsigned short* __restrict__ A, const unsigned short* __restrict__ Bt,
    unsigned short* __restrict__ bmb, unsigned short* __restrict__ cmb,
    unsigned short* __restrict__ zgb, unsigned short* __restrict__ xb)
{
    __shared__ __align__(16) unsigned short As[64 * 72];
    __shared__ __align__(16) unsigned short Bs[128 * 72];
    const int K = 256;
    int tid = threadIdx.x;
    int n0 = blockIdx.x * 128, m0 = blockIdx.y * 64;
    int w = tid >> 6, l = tid & 63;
    int mwave = (w >> 1) * 32, nwave = (w & 1) * 64;
    f32x4 acc[2][4] = {};
    int srow = tid >> 3, sc = (tid & 7) * 8;
    const unsigned short* Ap = A + (size_t)(m0 + srow) * K + sc;
    const unsigned short* Bp = Bt + (size_t)(n0 + srow) * K + sc;
    int lq = l & 15, lh = l >> 4;
    uint4 a0 = *(const uint4*)(Ap);
    uint4 a1 = *(const uint4*)(Ap + (size_t)32 * K);
    uint4 b0 = *(const uint4*)(Bp);
    uint4 b1 = *(const uint4*)(Bp + (size_t)32 * K);
    uint4 b2 = *(const uint4*)(Bp + (size_t)64 * K);
    uint4 b3 = *(const uint4*)(Bp + (size_t)96 * K);
    for (int k0 = 0; k0 < K; k0 += 64) {
        if (k0) __syncthreads();
        *(uint4*)&As[srow * 72 + sc] = a0;
        *(uint4*)&As[(srow + 32) * 72 + sc] = a1;
        *(uint4*)&Bs[srow * 72 + sc] = b0;
        *(uint4*)&Bs[(srow + 32) * 72 + sc] = b1;
        *(uint4*)&Bs[(srow + 64) * 72 + sc] = b2;
        *(uint4*)&Bs[(srow + 96) * 72 + sc] = b3;
        __syncthreads();
        if (k0 + 64 < K) {
            a0 = *(const uint4*)(Ap + k0 + 64);
            a1 = *(const uint4*)(Ap + (size_t)32 * K + k0 + 64);
            b0 = *(const uint4*)(Bp + k0 + 64);
            b1 = *(const uint4*)(Bp + (size_t)32 * K + k0 + 64);
            b2 = *(const uint4*)(Bp + (size_t)64 * K + k0 + 64);
            b3 = *(const uint4*)(Bp + (size_t)96 * K + k0 + 64);
        }
        #pragma unroll
        for (int kk = 0; kk < 2; kk++) {
            int kof = kk * 32 + lh * 8;
            s16x8 bfr[4];
            #pragma unroll
            for (int nf = 0; nf < 4; nf++)
                bfr[nf] = *(const s16x8*)&Bs[(nwave + nf * 16 + lq) * 72 + kof];
            #pragma unroll
            for (int mf = 0; mf < 2; mf++) {
                s16x8 af = *(const s16x8*)&As[(mwave + mf * 16 + lq) * 72 + kof];
                #pragma unroll
                for (int nf = 0; nf < 4; nf++)
                    acc[mf][nf] = __builtin_amdgcn_mfma_f32_16x16x32_bf16(af, bfr[nf], acc[mf][nf], 0, 0, 0);
            }
        }
    }
    #pragma unroll
    for (int mf = 0; mf < 2; mf++) {
        #pragma unroll
        for (int nf = 0; nf < 4; nf++) {
            int n = n0 + nwave + nf * 16 + lq;
            #pragma unroll
            for (int r = 0; r < 4; r++) {
                int m = m0 + mwave + mf * 16 + lh * 4 + r;
                float v = acc[mf][nf][r];
                if (n < 512)       bmb[(size_t)m * 512 + n] = f2bits(v);
                else if (n < 1024) cmb[(size_t)m * 512 + (n - 512)] = f2bits(v);
                else if (n < 1280) zgb[(size_t)m * 256 + (n - 1024)] = f2bits(siluf(v));
                else               xb[(size_t)m * 256 + (n - 1280)] = f2bits(v);
            }
        }
    }
}

// ======== combo2: gemm_s (blocks 0..191, BK=64, wave-scan) + conv_t (192..447) ========
__global__ __launch_bounds__(256) void s_conv_kernel(
    const unsigned short* __restrict__ cmb, const unsigned short* __restrict__ bmb,
    const float4* __restrict__ dtv4, const float* __restrict__ A_log,
    const float* __restrict__ theta, unsigned short* __restrict__ P,
    const unsigned short* __restrict__ xb, const float* __restrict__ cw,
    unsigned short* __restrict__ x2t)
{
    __shared__ __align__(16) char smem[39936];
    int blk = blockIdx.x;
    int tid = threadIdx.x;
    if (blk >= 192) {
        // ---- conv path ----
        int c = blk - 192;
        int bhid = c >> 2, tt = c & 3;
        int bk = bhid >> 2, h = bhid & 3;
        int t0 = tt * 64;
        float* tile = (float*)smem;     // 67*65 floats
        #pragma unroll
        for (int i = 0; i < 17; i++) {
            int idx = tid + i * 256;
            if (idx < 67 * 64) {
                int tr = idx >> 6, dd = idx & 63;
                int t = t0 - 3 + tr;
                tile[tr * 65 + dd] = (t >= 0)
                    ? bits2f(xb[(size_t)(bk * 256 + t) * 256 + h * 64 + dd]) : 0.f;
            }
        }
        __syncthreads();
        int wv_ = tid >> 6, lt = tid & 63;
        #pragma unroll 4
        for (int pi = 0; pi < 16; pi++) {
            int p = wv_ * 16 + pi;
            float4 wv = *(const float4*)(cw + (h * 64 + p) * 4);
            float acc = tile[lt * 65 + p] * wv.x + tile[(lt + 1) * 65 + p] * wv.y +
                        tile[(lt + 2) * 65 + p] * wv.z + tile[(lt + 3) * 65 + p] * wv.w;
            x2t[(size_t)(bhid * 64 + p) * 256 + t0 + lt] = f2bits(siluf(acc));
        }
        return;
    }
    // ---- gemm_s path ----
    int map = blk >> 6;              // 0,1,2
    int bh = blk & 63;
    int bx = (map == 2) ? 1 : 0;
    int by = (map == 0) ? 0 : 1;
    int bk = bh >> 2, h = bh & 3;
    unsigned short* As = (unsigned short*)smem;            // 128*72
    unsigned short* Bs = As + 128 * 72;                    // 128*72
    float* mAs = (float*)(smem + 36864);                   // 256
    float* phs = mAs + 256;
    float* dss = phs + 256;
    int srow = tid >> 3, sc = (tid & 7) * 8;
    const unsigned short* Ap = cmb + (size_t)(bk * 256 + by * 128 + srow) * 512 + h * 128 + sc;
    const unsigned short* Bp = bmb + (size_t)(bk * 256 + bx * 128 + srow) * 512 + h * 128 + sc;
    // issue prologue loads before the scan so they overlap it
    uint4 a0 = *(const uint4*)(Ap);
    uint4 a1 = *(const uint4*)(Ap + (size_t)32 * 512);
    uint4 a2 = *(const uint4*)(Ap + (size_t)64 * 512);
    uint4 a3 = *(const uint4*)(Ap + (size_t)96 * 512);
    uint4 b0 = *(const uint4*)(Bp);
    uint4 b1 = *(const uint4*)(Bp + (size_t)32 * 512);
    uint4 b2 = *(const uint4*)(Bp + (size_t)64 * 512);
    uint4 b3 = *(const uint4*)(Bp + (size_t)96 * 512);
    {
        // wave-parallel inclusive scan over t=0..255 of (dt*A, dt*theta)
        float4 dv = dtv4[bk * 256 + tid];
        float dth = (h == 0) ? dv.x : (h == 1) ? dv.y : (h == 2) ? dv.z : dv.w;
        float Ah = -__expf(A_log[h]);
        float th = theta[h];
        float a = dth * Ah, p = dth * th;
        dss[tid] = dth;
        int lane = tid & 63, wv = tid >> 6;
        #pragma unroll
        for (int off = 1; off < 64; off <<= 1) {
            float ta = __shfl_up(a, off, 64);
            float tp = __shfl_up(p, off, 64);
            if (lane >= off) { a += ta; p += tp; }
        }
        if (lane == 63) { mAs[wv] = a; phs[wv] = p; }
        __syncthreads();
        float offA = 0.f, offP = 0.f;
        #pragma unroll
        for (int j = 0; j < 3; j++)
            if (j < wv) { offA += mAs[j]; offP += phs[j]; }
        __syncthreads();
        mAs[tid] = a + offA;
        phs[tid] = p + offP;
        __syncthreads();
    }
    int w = tid >> 6, l = tid & 63;
    int mwave = (w >> 1) * 64, nwave = (w & 1) * 64;
    int lq = l & 15, lh = l >> 4;
    unsigned short* Pout = P + (size_t)bh * 65536;
    f32x4 acc[4][4] = {};
    for (int k0 = 0; k0 < 128; k0 += 64) {
        __syncthreads();
        *(uint4*)&As[srow * 72 + sc] = a0;
        *(uint4*)&As[(srow + 32) * 72 + sc] = a1;
        *(uint4*)&As[(srow + 64) * 72 + sc] = a2;
        *(uint4*)&As[(srow + 96) * 72 + sc] = a3;
        *(uint4*)&Bs[srow * 72 + sc] = b0;
        *(uint4*)&Bs[(srow + 32) * 72 + sc] = b1;
        *(uint4*)&Bs[(srow + 64) * 72 + sc] = b2;
        *(uint4*)&Bs[(srow + 96) * 72 + sc] = b3;
        __syncthreads();
        if (k0 + 64 < 128) {
            a0 = *(const uint4*)(Ap + k0 + 64);
            a1 = *(const uint4*)(Ap + (size_t)32 * 512 + k0 + 64);
            a2 = *(const uint4*)(Ap + (size_t)64 * 512 + k0 + 64);
            a3 = *(const uint4*)(Ap + (size_t)96 * 512 + k0 + 64);
            b0 = *(const uint4*)(Bp + k0 + 64);
            b1 = *(const uint4*)(Bp + (size_t)32 * 512 + k0 + 64);
            b2 = *(const uint4*)(Bp + (size_t)64 * 512 + k0 + 64);
            b3 = *(const uint4*)(Bp + (size_t)96 * 512 + k0 + 64);
        }
        #pragma unroll
        for (int kk = 0; kk < 2; kk++) {
            int kof = kk * 32 + lh * 8;
            s16x8 bfr[4];
            #pragma unroll
            for (int nf = 0; nf < 4; nf++)
                bfr[nf] = *(const s16x8*)&Bs[(nwave + nf * 16 + lq) * 72 + kof];
            #pragma unroll
            for (int mf = 0; mf < 4; mf++) {
                s16x8 af = *(const s16x8*)&As[(mwave + mf * 16 + lq) * 72 + kof];
                #pragma unroll
                for (int nf = 0; nf < 4; nf++)
                    acc[mf][nf] = __builtin_amdgcn_mfma_f32_16x16x32_bf16(af, bfr[nf], acc[mf][nf], 0, 0, 0);
            }
        }
    }
    #pragma unroll
    for (int mf = 0; mf < 4; mf++) {
        float tmv[4], tpv[4]; int tg[4];
        #pragma unroll
        for (int r = 0; r < 4; r++) {
            tg[r] = by * 128 + mwave + mf * 16 + lh * 4 + r;
            tmv[r] = mAs[tg[r]];
            tpv[r] = phs[tg[r]];
        }
        #pragma unroll
        for (int nf = 0; nf < 4; nf++) {
            int s = bx * 128 + nwave + nf * 16 + lq;
            float ms = mAs[s];
            float ps = phs[s];
            float ds = dss[s];
            #pragma unroll
            for (int r = 0; r < 4; r++) {
                float wgt = (s <= tg[r])
                    ? __expf(tmv[r] - ms) * __cosf(tpv[r] - ps) * ds : 0.f;
                Pout[tg[r] * 256 + s] = f2bits(acc[mf][nf][r] * wgt);
            }
        }
    }
}

// ------- batched Y = P @ X^T (32x64 tile, triangular K-clip, 512 blocks) -------
__global__ __launch_bounds__(256) void gemm_y(
    const unsigned short* __restrict__ P, const unsigned short* __restrict__ x2t,
    const unsigned short* __restrict__ zgb, const float* __restrict__ Dsk,
    unsigned short* __restrict__ ygb)
{
    int by = blockIdx.x, bh = blockIdx.y;
    int bk = bh >> 2, h = bh & 3;
    int t0 = by * 32;
    int tid = threadIdx.x;
    int w = tid >> 6, l = tid & 63;
    int mw = (w >> 1) * 16, nw = (w & 1) * 32;
    int lq = l & 15, lh = l >> 4;
    __shared__ __align__(16) unsigned short As[32 * 72];
    __shared__ __align__(16) unsigned short Bs[64 * 72];
    f32x4 acc[2] = {};
    int srow = tid >> 3, sc = (tid & 7) * 8;
    const unsigned short* Ap = P + (size_t)bh * 65536 + (size_t)(t0 + srow) * 256 + sc;
    const unsigned short* Bp = x2t + (size_t)bh * 16384 + (size_t)srow * 256 + sc;
    int kmax = ((by >> 1) + 1) * 64;
    uint4 a0 = *(const uint4*)(Ap);
    uint4 b0 = *(const uint4*)(Bp);
    uint4 b1 = *(const uint4*)(Bp + (size_t)32 * 256);
    for (int k0 = 0; k0 < kmax; k0 += 64) {
        if (k0) __syncthreads();
        *(uint4*)&As[(srow & 31) * 72 + sc] = a0;
        *(uint4*)&Bs[srow * 72 + sc] = b0;
        *(uint4*)&Bs[(srow + 32) * 72 + sc] = b1;
        __syncthreads();
        if (k0 + 64 < kmax) {
            a0 = *(const uint4*)(Ap + k0 + 64);
            b0 = *(const uint4*)(Bp + k0 + 64);
            b1 = *(const uint4*)(Bp + (size_t)32 * 256 + k0 + 64);
        }
        #pragma unroll
        for (int kk = 0; kk < 2; kk++) {
            int kof = kk * 32 + lh * 8;
            s16x8 af = *(const s16x8*)&As[(mw + lq) * 72 + kof];
            #pragma unroll
            for (int nf = 0; nf < 2; nf++) {
                s16x8 bf = *(const s16x8*)&Bs[(nw + nf * 16 + lq) * 72 + kof];
                acc[nf] = __builtin_amdgcn_mfma_f32_16x16x32_bf16(af, bf, acc[nf], 0, 0, 0);
            }
        }
    }
    float dsk = Dsk[h];
    #pragma unroll
    for (int nf = 0; nf < 2; nf++) {
        int p = nw + nf * 16 + lq;
        #pragma unroll
        for (int r = 0; r < 4; r++) {
            int t = t0 + mw + lh * 4 + r;
            float xv = bits2f(x2t[(size_t)bh * 16384 + p * 256 + t]);
            float zg = bits2f(zgb[(size_t)(bk * 256 + t) * 256 + h * 64 + p]);
            ygb[(size_t)(bk * 256 + t) * 256 + h * 64 + p] =
                f2bits((acc[nf][r] + dsk * xv) * zg);
        }
    }
}

// ======== mid_kernel v4: 16 rows/block, 256 blocks, 512 thr / 8 waves ========
// continuous 2-deep register prefetch across all phases (issue-early/write-late)
__global__ __launch_bounds__(512) void mid_kernel(
    const unsigned short* __restrict__ ygb, const unsigned short* __restrict__ wts,
    const float* __restrict__ zin,
    const float* __restrict__ g2, const float* __restrict__ b2,
    const float* __restrict__ qbias, const float* __restrict__ obias,
    const float* __restrict__ g3, const float* __restrict__ b3,
    float* __restrict__ z2, unsigned short* __restrict__ zfb)
{
    __shared__ __align__(16) char smem[65024];
    unsigned short* Bs = (unsigned short*)smem;             // 256*72*2 = 36864
    unsigned short* As = (unsigned short*)(smem + 36864);   // 16*72*2  = 2304
    unsigned short* zn = (unsigned short*)(smem + 39168);   // 16*264*2 = 8448 (znb, later ob)
    float* z1s = (float*)(smem + 47616);                    // 16*256*4 = 16384
    float (*partS)[8] = (float(*)[8])(smem + 64000);        // 512
    float (*partQ)[8] = (float(*)[8])(smem + 64512);        // 512
    unsigned short* qk = (unsigned short*)smem;             // overlay Bs: 16*776*2 = 24832

    const int K = 256;
    int tid = threadIdx.x;
    int m0 = blockIdx.x * 16;
    int w = tid >> 6, l = tid & 63;
    int nw = w * 32;                 // 8 waves x 32 cols
    int lq = l & 15, lh = l >> 4;
    int srow = tid >> 3, sc = (tid & 7) * 8;   // srow 0..63

    const unsigned short* BpO  = wts + W_OUT + (size_t)srow * K + sc;
    const unsigned short* BpQ0 = wts + W_QKV + (size_t)srow * K + sc;
    const unsigned short* BpQ1 = BpQ0 + (size_t)256 * K;
    const unsigned short* BpQ2 = BpQ0 + (size_t)512 * K;
    const unsigned short* BpA  = wts + W_AO + (size_t)srow * K + sc;

    uint4 wA0, wA1, wA2, wA3, wB0, wB1, wB2, wB3;

#define LOADW(P, BASE, KO) do { \
    P##0 = *(const uint4*)((BASE) + (KO)); \
    P##1 = *(const uint4*)((BASE) + (size_t)64 * K + (KO)); \
    P##2 = *(const uint4*)((BASE) + (size_t)128 * K + (KO)); \
    P##3 = *(const uint4*)((BASE) + (size_t)192 * K + (KO)); \
} while (0)
#define STORE_BS(P) do { \
    *(uint4*)&Bs[srow * 72 + sc] = P##0; \
    *(uint4*)&Bs[(srow + 64) * 72 + sc] = P##1; \
    *(uint4*)&Bs[(srow + 128) * 72 + sc] = P##2; \
    *(uint4*)&Bs[(srow + 192) * 72 + sc] = P##3; \
} while (0)
#define MM_ZN(AQ, KO) do { \
    _Pragma("unroll") \
    for (int kk = 0; kk < 2; kk++) { \
        int kof = kk * 32 + lh * 8; \
        s16x8 af = *(const s16x8*)&zn[lq * 264 + (KO) + kof]; \
        _Pragma("unroll") \
        for (int nf = 0; nf < 2; nf++) { \
            s16x8 bf = *(const s16x8*)&Bs[(nw + nf * 16 + lq) * 72 + kof]; \
            AQ[nf] = __builtin_amdgcn_mfma_f32_16x16x32_bf16(af, bf, AQ[nf], 0, 0, 0); \
        } \
    } \
} while (0)
#define MM_AS(AQ) do { \
    _Pragma("unroll") \
    for (int kk = 0; kk < 2; kk++) { \
        int kof = kk * 32 + lh * 8; \
        s16x8 af = *(const s16x8*)&As[lq * 72 + kof]; \
        _Pragma("unroll") \
        for (int nf = 0; nf < 2; nf++) { \
            s16x8 bf = *(const s16x8*)&Bs[(nw + nf * 16 + lq) * 72 + kof]; \
            AQ[nf] = __builtin_amdgcn_mfma_f32_16x16x32_bf16(af, bf, AQ[nf], 0, 0, 0); \
        } \
    } \
} while (0)

    // ------------- phase 1: z1 = ygb(gathered) @ Wout + z ; zn = LN2(z1) -------------
    f32x4 acc1[2] = {};
    {
        int rb = m0 + (srow & 15);
        int irow = ((rb >> 11) * 8 + (rb & 7)) * 256 + ((rb >> 3) & 255);
        const unsigned short* Ap = ygb + (size_t)irow * K + sc;
        LOADW(wA, BpO, 0);
        LOADW(wB, BpO, 64);
        uint4 aP = *(const uint4*)(Ap);
        uint4 aQ;
        // r0 (k0=0)
        __syncthreads();
        if (tid < 128) *(uint4*)&As[srow * 72 + sc] = aP;
        STORE_BS(wA);
        __syncthreads();
        aQ = *(const uint4*)(Ap + 64);
        LOADW(wA, BpO, 128);
        MM_AS(acc1);
        // r1 (k0=64)
        __syncthreads();
        if (tid < 128) *(uint4*)&As[srow * 72 + sc] = aQ;
        STORE_BS(wB);
        __syncthreads();
        aP = *(const uint4*)(Ap + 128);
        LOADW(wB, BpO, 192);
        MM_AS(acc1);
        // r2 (k0=128) — prefetch QKV pass0 k0=0
        __syncthreads();
        if (tid < 128) *(uint4*)&As[srow * 72 + sc] = aP;
        STORE_BS(wA);
        __syncthreads();
        aQ = *(const uint4*)(Ap + 192);
        LOADW(wA, BpQ0, 0);
        MM_AS(acc1);
        // r3 (k0=192) — prefetch QKV pass0 k0=64
        __syncthreads();
        if (tid < 128) *(uint4*)&As[srow * 72 + sc] = aQ;
        STORE_BS(wB);
        __syncthreads();
        LOADW(wB, BpQ0, 64);
        MM_AS(acc1);
        // epilogue: residual + LN2 (QKV pass0 loads in flight)
        #pragma unroll
        for (int r = 0; r < 4; r++) {
            int row = lh * 4 + r;
            float s = 0.f, q = 0.f;
            #pragma unroll
            for (int nf = 0; nf < 2; nf++) {
                float v = acc1[nf][r] + zin[(size_t)(m0 + row) * 256 + nw + nf * 16 + lq];
                acc1[nf][r] = v;
                s += v; q += v * v;
            }
            #pragma unroll
            for (int off = 1; off < 16; off <<= 1) {
                s += __shfl_xor(s, off, 64);
                q += __shfl_xor(q, off, 64);
            }
            if (lq == 0) { partS[row][w] = s; partQ[row][w] = q; }
        }
        __syncthreads();
        float gv[2], bbv[2];
        #pragma unroll
        for (int nf = 0; nf < 2; nf++) {
            gv[nf] = g2[nw + nf * 16 + lq];
            bbv[nf] = b2[nw + nf * 16 + lq];
        }
        #pragma unroll
        for (int r = 0; r < 4; r++) {
            int row = lh * 4 + r;
            float sum = 0.f, sq = 0.f;
            #pragma unroll
            for (int j = 0; j < 8; j++) { sum += partS[row][j]; sq += partQ[row][j]; }
            float mean = sum * (1.f / 256.f);
            float var = sq * (1.f / 256.f) - mean * mean;
            float rstd = rsqrtf(var + 1e-5f);
            #pragma unroll
            for (int nf = 0; nf < 2; nf++) {
                int n = nw + nf * 16 + lq;
                float v = acc1[nf][r];
                z1s[row * 256 + n] = v;
                zn[row * 264 + n] = f2bits((v - mean) * rstd * gv[nf] + bbv[nf]);
            }
        }
    }

    // ------------- phase 2: qkv = zn @ Wqkv, 12 rounds, continuous 2-deep -------------
    f32x4 aq0[2] = {}, aq1[2] = {}, aq2[2] = {};
#define RND(P, AQ, KO, NBASE, NKO) do { \
    __syncthreads(); \
    STORE_BS(P); \
    __syncthreads(); \
    LOADW(P, NBASE, NKO); \
    MM_ZN(AQ, KO); \
} while (0)
#define RND_NL(P, AQ, KO) do { \
    __syncthreads(); \
    STORE_BS(P); \
    __syncthreads(); \
    MM_ZN(AQ, KO); \
} while (0)
    RND(wA, aq0, 0,   BpQ0, 128);
    RND(wB, aq0, 64,  BpQ0, 192);
    RND(wA, aq0, 128, BpQ1, 0);
    RND(wB, aq0, 192, BpQ1, 64);
    RND(wA, aq1, 0,   BpQ1, 128);
    RND(wB, aq1, 64,  BpQ1, 192);
    RND(wA, aq1, 128, BpQ2, 0);
    RND(wB, aq1, 192, BpQ2, 64);
    RND(wA, aq2, 0,   BpQ2, 128);
    RND(wB, aq2, 64,  BpQ2, 192);
    RND(wA, aq2, 128, BpA, 0);      // prefetch Wao k0=0 — flies through attention
    RND(wB, aq2, 192, BpA, 64);     // prefetch Wao k0=64

    // ------------- phase 3: qkv -> LDS (+bias), then attention -------------
    __syncthreads();   // all Bs reads done; safe to overwrite as qk
#define QKV_STORE(PIDX, AQ) do { \
    _Pragma("unroll") \
    for (int nf = 0; nf < 2; nf++) { \
        int n = (PIDX) * 256 + nw + nf * 16 + lq; \
        float bb = qbias[n]; \
        _Pragma("unroll") \
        for (int r = 0; r < 4; r++) \
            qk[(lh * 4 + r) * 776 + n] = f2bits(AQ[nf][r] + bb); \
    } \
} while (0)
    QKV_STORE(0, aq0);
    QKV_STORE(1, aq1);
    QKV_STORE(2, aq2);
#undef QKV_STORE
    __syncthreads();
    {
        int hh = w & 3;          // head
        int half = w >> 2;       // which pair of window-groups
        int d = l;
        #pragma unroll
        for (int wi = 0; wi < 2; wi++) {
            int w4 = half * 2 + wi;
            int r0 = w4 * 4;
            float qv[4], kv[4], vv[4];
            #pragma unroll
            for (int j = 0; j < 4; j++) {
                qv[j] = bits2f(qk[(r0 + j) * 776 + hh * 64 + d]);
                kv[j] = bits2f(qk[(r0 + j) * 776 + 256 + hh * 64 + d]);
                vv[j] = bits2f(qk[(r0 + j) * 776 + 512 + hh * 64 + d]);
            }
            float sc_[4][4];
            #pragma unroll
            for (int qi = 0; qi < 4; qi++)
                #pragma unroll
                for (int ki = 0; ki < 4; ki++) {
                    float v = qv[qi] * kv[ki];
                    #pragma unroll
                    for (int off = 32; off; off >>= 1) v += __shfl_xor(v, off, 64);
                    sc_[qi][ki] = v * 0.125f;
                }
            #pragma unroll
            for (int qi = 0; qi < 4; qi++) {
                float mx = fmaxf(fmaxf(sc_[qi][0], sc_[qi][1]), fmaxf(sc_[qi][2], sc_[qi][3]));
                float e0 = __expf(sc_[qi][0] - mx), e1 = __expf(sc_[qi][1] - mx);
                float e2 = __expf(sc_[qi][2] - mx), e3 = __expf(sc_[qi][3] - mx);
                float inv = 1.f / (e0 + e1 + e2 + e3);
                float ov = (e0 * vv[0] + e1 * vv[1] + e2 * vv[2] + e3 * vv[3]) * inv;
                zn[(r0 + qi) * 264 + hh * 64 + d] = f2bits(ov);   // ob overlays zn
            }
        }
    }

    // ------------- phase 4: z2 = ob @ Wao + obias + z1 ; zfb = LN3(z2) -------------
    {
        f32x4 ac4[2] = {};
        RND(wA, ac4, 0,  BpA, 128);
        RND(wB, ac4, 64, BpA, 192);
        RND_NL(wA, ac4, 128);
        RND_NL(wB, ac4, 192);
        float bv[2], gv[2], bbv[2];
        #pragma unroll
        for (int nf = 0; nf < 2; nf++) {
            int n = nw + nf * 16 + lq;
            bv[nf] = obias[n];
            gv[nf] = g3[n];
            bbv[nf] = b3[n];
        }
        #pragma unroll
        for (int r = 0; r < 4; r++) {
            int row = lh * 4 + r;
            float s = 0.f, q = 0.f;
            #pragma unroll
            for (int nf = 0; nf < 2; nf++) {
                float v = ac4[nf][r] + bv[nf] + z1s[row * 256 + nw + nf * 16 + lq];
                ac4[nf][r] = v;
                s += v; q += v * v;
            }
            #pragma unroll
            for (int off = 1; off < 16; off <<= 1) {
                s += __shfl_xor(s, off, 64);
                q += __shfl_xor(q, off, 64);
            }
            if (lq == 0) { partS[row][w] = s; partQ[row][w] = q; }
        }
        __syncthreads();
        #pragma unroll
        for (int r = 0; r < 4; r++) {
            int row = lh * 4 + r;
            float sum = 0.f, sq = 0.f;
            #pragma unroll
            for (int j = 0; j < 8; j++) { sum += partS[row][j]; sq += partQ[row][j]; }
            float mean = sum * (1.f / 256.f);
            float var = sq * (1.f / 256.f) - mean * mean;
            float rstd = rsqrtf(var + 1e-5f);
            size_t ro = (size_t)(m0 + row) * 256;
            #pragma unroll
            for (int nf = 0; nf < 2; nf++) {
                int n = nw + nf * 16 + lq;
                float v = ac4[nf][r];
                z2[ro + n] = v;
                zfb[ro + n] = f2bits((v - mean) * rstd * gv[nf] + bbv[nf]);
            }
        }
    }
#undef RND
#undef RND_NL
#undef LOADW
#undef STORE_BS
#undef MM_ZN
#undef MM_AS
}

// ---- gemm_gu2: 64x64 tile, dual-accumulator G/U, 1024 blocks (4/CU) ----
__global__ __launch_bounds__(256) void gemm_gu2(
    const unsigned short* __restrict__ A, const unsigned short* __restrict__ Wgu,
    unsigned short* __restrict__ gg)
{
    const int K = 256;
    __shared__ __align__(16) unsigned short As[64 * 72];
    __shared__ __align__(16) unsigned short Bgs[64 * 72];
    __shared__ __align__(16) unsigned short Bus[64 * 72];
    int tid = threadIdx.x;
    int n0 = blockIdx.x * 64, m0 = blockIdx.y * 64;
    int w = tid >> 6, l = tid & 63;
    int mwave = (w >> 1) * 32, nwave = (w & 1) * 32;
    int lq = l & 15, lh = l >> 4;
    f32x4 ag[2][2] = {}, au[2][2] = {};
    int srow = tid >> 3, sc = (tid & 7) * 8;
    const unsigned short* Ap = A + (size_t)(m0 + srow) * K + sc;
    const unsigned short* Bgp = Wgu + (size_t)(n0 + srow) * K + sc;
    const unsigned short* Bup = Wgu + (size_t)(1024 + n0 + srow) * K + sc;
    uint4 a0 = *(const uint4*)(Ap);
    uint4 a1 = *(const uint4*)(Ap + (size_t)32 * K);
    uint4 bg0 = *(const uint4*)(Bgp);
    uint4 bg1 = *(const uint4*)(Bgp + (size_t)32 * K);
    uint4 bu0 = *(const uint4*)(Bup);
    uint4 bu1 = *(const uint4*)(Bup + (size_t)32 * K);
    for (int k0 = 0; k0 < K; k0 += 64) {
        if (k0) __syncthreads();
        *(uint4*)&As[srow * 72 + sc] = a0;
        *(uint4*)&As[(srow + 32) * 72 + sc] = a1;
        *(uint4*)&Bgs[srow * 72 + sc] = bg0;
        *(uint4*)&Bgs[(srow + 32) * 72 + sc] = bg1;
        *(uint4*)&Bus[srow * 72 + sc] = bu0;
        *(uint4*)&Bus[(srow + 32) * 72 + sc] = bu1;
        __syncthreads();
        if (k0 + 64 < K) {
            a0 = *(const uint4*)(Ap + k0 + 64);
            a1 = *(const uint4*)(Ap + (size_t)32 * K + k0 + 64);
            bg0 = *(const uint4*)(Bgp + k0 + 64);
            bg1 = *(const uint4*)(Bgp + (size_t)32 * K + k0 + 64);
            bu0 = *(const uint4*)(Bup + k0 + 64);
            bu1 = *(const uint4*)(Bup + (size_t)32 * K + k0 + 64);
        }
        #pragma unroll
        for (int kk = 0; kk < 2; kk++) {
            int kof = kk * 32 + lh * 8;
            s16x8 bgr[2], bur[2];
            #pragma unroll
            for (int nf = 0; nf < 2; nf++) {
                bgr[nf] = *(const s16x8*)&Bgs[(nwave + nf * 16 + lq) * 72 + kof];
                bur[nf] = *(const s16x8*)&Bus[(nwave + nf * 16 + lq) * 72 + kof];
            }
            #pragma unroll
            for (int mf = 0; mf < 2; mf++) {
                s16x8 af = *(const s16x8*)&As[(mwave + mf * 16 + lq) * 72 + kof];
                #pragma unroll
                for (int nf = 0; nf < 2; nf++) {
                    ag[mf][nf] = __builtin_amdgcn_mfma_f32_16x16x32_bf16(af, bgr[nf], ag[mf][nf], 0, 0, 0);
                    au[mf][nf] = __builtin_amdgcn_mfma_f32_16x16x32_bf16(af, bur[nf], au[mf][nf], 0, 0, 0);
                }
            }
        }
    }
    #pragma unroll
    for (int mf = 0; mf < 2; mf++) {
        #pragma unroll
        for (int nf = 0; nf < 2; nf++) {
            int n = n0 + nwave + nf * 16 + lq;
            #pragma unroll
            for (int r = 0; r < 4; r++) {
                int m = m0 + mwave + mf * 16 + lh * 4 + r;
                gg[(size_t)m * 1024 + n] = f2bits(siluf(ag[mf][nf][r]) * au[mf][nf][r]);
            }
        }
    }
}

// ------- gemm_d2 (64x32 tile, BK=64, 2-deep register prefetch): out = gg @ Wd^T + resid -------
__global__ __launch_bounds__(256) void gemm_d2(
    const unsigned short* __restrict__ gg, const unsigned short* __restrict__ Bt,
    const float* __restrict__ resid, float* __restrict__ out)
{
    __shared__ __align__(16) unsigned short As[64 * 72];
    __shared__ __align__(16) unsigned short Bs[32 * 72];
    const int K = 1024, N = 256;
    int tid = threadIdx.x;
    int n0 = blockIdx.x * 32, m0 = blockIdx.y * 64;
    int w = tid >> 6, l = tid & 63;
    int mw = (w >> 1) * 32, nw = (w & 1) * 16;
    f32x4 acc[2] = {};
    int srow = tid >> 3, sc = (tid & 7) * 8;
    const unsigned short* Ap = gg + (size_t)(m0 + srow) * K + sc;
    const unsigned short* Bp = Bt + (size_t)(n0 + (srow & 31)) * K + sc;
    int lq = l & 15, lh = l >> 4;
    uint4 xA0 = *(const uint4*)(Ap);
    uint4 xA1 = *(const uint4*)(Ap + (size_t)32 * K);
    uint4 yA  = *(const uint4*)(Bp);
    uint4 xB0 = *(const uint4*)(Ap + 64);
    uint4 xB1 = *(const uint4*)(Ap + (size_t)32 * K + 64);
    uint4 yB  = *(const uint4*)(Bp + 64);
    for (int k0 = 0; k0 < K; k0 += 128) {
        __syncthreads();
        *(uint4*)&As[srow * 72 + sc] = xA0;
        *(uint4*)&As[(srow + 32) * 72 + sc] = xA1;
        *(uint4*)&Bs[(srow & 31) * 72 + sc] = yA;
        __syncthreads();
        if (k0 + 128 < K) {
            xA0 = *(const uint4*)(Ap + k0 + 128);
            xA1 = *(const uint4*)(Ap + (size_t)32 * K + k0 + 128);
            yA  = *(const uint4*)(Bp + k0 + 128);
        }
        #pragma unroll
        for (int kk = 0; kk < 2; kk++) {
            int kof = kk * 32 + lh * 8;
            s16x8 bf = *(const s16x8*)&Bs[(nw + lq) * 72 + kof];
            #pragma unroll
            for (int mf = 0; mf < 2; mf++) {
                s16x8 af = *(const s16x8*)&As[(mw + mf * 16 + lq) * 72 + kof];
                acc[mf] = __builtin_amdgcn_mfma_f32_16x16x32_bf16(af, bf, acc[mf], 0, 0, 0);
            }
        }
        __syncthreads();
        *(uint4*)&As[srow * 72 + sc] = xB0;
        *(uint4*)&As[(srow + 32) * 72 + sc] = xB1;
        *(uint4*)&Bs[(srow & 31) * 72 + sc] = yB;
        __syncthreads();
        if (k0 + 192 < K) {
            xB0 = *(const uint4*)(Ap + k0 + 192);
            xB1 = *(const uint4*)(Ap + (size_t)32 * K + k0 + 192);
            yB  = *(const uint4*)(Bp + k0 + 192);
        }
        #pragma unroll
        for (int kk = 0; kk < 2; kk++) {
            int kof = kk * 32 + lh * 8;
            s16x8 bf = *(const s16x8*)&Bs[(nw + lq) * 72 + kof];
            #pragma unroll
            for (int mf = 0; mf < 2; mf++) {
                s16x8 af = *(const s16x8*)&As[(mw + mf * 16 + lq) * 72 + kof];
                acc[mf] = __builtin_amdgcn_mfma_f32_16x16x32_bf16(af, bf, acc[mf], 0, 0, 0);
            }
        }
    }
    int n = n0 + nw + lq;
    #pragma unroll
    for (int mf = 0; mf < 2; mf++) {
        #pragma unroll
        for (int r = 0; r < 4; r++) {
            int m = m0 + mw + mf * 16 + lh * 4 + r;
            out[(size_t)m * N + n] = acc[mf][r] + resid[(size_t)m * N + n];
        }
    }
}

extern "C" void kernel_launch(void* const* d_in, const int* in_sizes, int n_in,
                              void* d_out, int out_size, void* d_ws, size_t ws_size,
                              hipStream_t stream)
{
    const float* z         = (const float*)d_in[0];
    const float* ln1_g     = (const float*)d_in[1];
    const float* ln1_b     = (const float*)d_in[2];
    const float* Wx        = (const float*)d_in[3];
    const float* conv_w    = (const float*)d_in[4];
    const float* Wz        = (const float*)d_in[5];
    const float* Wb        = (const float*)d_in[6];
    const float* Wc        = (const float*)d_in[7];
    const float* Wdt       = (const float*)d_in[8];
    const float* dt_bias   = (const float*)d_in[9];
    const float* A_log     = (const float*)d_in[10];
    const float* theta     = (const float*)d_in[11];
    const float* D_skip    = (const float*)d_in[12];
    const float* mimo_U    = (const float*)d_in[13];
    const float* mimo_V    = (const float*)d_in[14];
    const float* Wout      = (const float*)d_in[15];
    const float* ln2_g     = (const float*)d_in[16];
    const float* ln2_b     = (const float*)d_in[17];
    const float* attn_in_w = (const float*)d_in[18];
    const float* attn_in_b = (const float*)d_in[19];
    const float* attn_out_w= (const float*)d_in[20];
    const float* attn_out_b= (const float*)d_in[21];
    const float* ln3_g     = (const float*)d_in[22];
    const float* ln3_b     = (const float*)d_in[23];
    const float* Wg        = (const float*)d_in[24];
    const float* Wu        = (const float*)d_in[25];
    const float* Wd        = (const float*)d_in[26];

    float* W = (float*)d_ws;
    unsigned short* wts = (unsigned short*)W;
    unsigned short* ub  = (unsigned short*)(W + OFF_UB);
    float4* dtv4        = (float4*)(W + OFF_DTV);
    unsigned short* bmb = (unsigned short*)(W + OFF_BMB);
    unsigned short* cmb = (unsigned short*)(W + OFF_CMB);
    unsigned short* zgb = (unsigned short*)(W + OFF_ZGB);
    unsigned short* xb  = (unsigned short*)(W + OFF_XB);
    unsigned short* x2t = (unsigned short*)(W + OFF_X2T);
    unsigned short* pbuf= (unsigned short*)(W + OFF_P);
    unsigned short* ygb = (unsigned short*)(W + OFF_YGB);
    float* z2           = W + OFF_Z2;
    unsigned short* zfb = (unsigned short*)(W + OFF_ZFB);
    unsigned short* gg  = (unsigned short*)(W + OFF_GG);

    prep_ln1_kernel<<<4464, 256, 0, stream>>>(
        Wx, Wb, Wc, Wz, Wout, attn_in_w, attn_out_w, Wg, Wu, Wd, mimo_U, mimo_V,
        wts, z, ln1_g, ln1_b, Wdt, dt_bias, ub, dtv4);
    gemm_bczx<<<dim3(12, 64), 256, 0, stream>>>(ub, wts + W_BCZX, bmb, cmb, zgb, xb);
    s_conv_kernel<<<448, 256, 0, stream>>>(cmb, bmb, dtv4, A_log, theta, pbuf,
                                           xb, conv_w, x2t);
    gemm_y<<<dim3(8, 64), 256, 0, stream>>>(pbuf, x2t, zgb, D_skip, ygb);
    mid_kernel<<<256, 512, 0, stream>>>(ygb, wts, z, ln2_g, ln2_b,
                                        attn_in_b, attn_out_b, ln3_g, ln3_b,
                                        z2, zfb);
    gemm_gu2<<<dim3(16, 64), 256, 0, stream>>>(zfb, wts + W_GU, gg);
    gemm_d2<<<dim3(8, 64), 256, 0, stream>>>(gg, wts + W_D, z2, (float*)d_out);
}